// Round 1
// baseline (391.756 us; speedup 1.0000x reference)
//
#include <hip/hip_runtime.h>
#include <hip/hip_bf16.h>

// Embedding gather: out[r, :] = weight[indices[r], :]
// indices: 16384*50 = 819200 int32, weight: 1,000,000 x 64 fp32,
// out: 819200 x 64 fp32.
//
// Each row is 64 fp32 = 256 B = 16 lanes * float4. 16 consecutive lanes
// handle one row -> one coalesced 256B read (the gathered row) + one
// coalesced 256B write per 16-lane group. Wave64 covers 4 rows.

#define EMBED_DIM 64
#define LANES_PER_ROW 16  // 64 floats / 4 floats-per-lane

__global__ __launch_bounds__(256) void embed_gather_kernel(
    const int* __restrict__ indices,
    const float4* __restrict__ weight,   // row r starts at weight[r*16]
    float4* __restrict__ out,            // row r starts at out[r*16]
    int num_rows) {
    int tid = blockIdx.x * blockDim.x + threadIdx.x;
    int row = tid >> 4;              // /16
    int lane = tid & (LANES_PER_ROW - 1);
    if (row >= num_rows) return;

    int src = indices[row];          // broadcast across the 16-lane group (L1 hit)
    // gathered read: 16 lanes * 16B = 256B contiguous from the table row
    float4 v = weight[(size_t)src * LANES_PER_ROW + lane];
    // coalesced write
    out[(size_t)row * LANES_PER_ROW + lane] = v;
}

extern "C" void kernel_launch(void* const* d_in, const int* in_sizes, int n_in,
                              void* d_out, int out_size, void* d_ws, size_t ws_size,
                              hipStream_t stream) {
    const int* indices = (const int*)d_in[0];
    const float4* weight = (const float4*)d_in[1];
    float4* out = (float4*)d_out;

    int num_rows = in_sizes[0];               // 819200
    int total_threads = num_rows * LANES_PER_ROW;
    int block = 256;
    int grid = (total_threads + block - 1) / block;

    embed_gather_kernel<<<grid, block, 0, stream>>>(indices, weight, out, num_rows);
}

// Round 3
// 391.350 us; speedup vs baseline: 1.0010x; 1.0010x over previous
//
#include <hip/hip_runtime.h>
#include <hip/hip_bf16.h>

// Embedding gather: out[r, :] = weight[indices[r], :]
// indices: 819200 int32, weight: 1,000,000 x 64 fp32 (244 MiB), out: 819200 x 64 fp32.
//
// R3 = R2 with native vector types (ext_vector_type) so
// __builtin_nontemporal_store compiles:
//  - 4 rows per thread: one broadcast int4 index load, then 4 INDEPENDENT
//    16B gathers in flight (4x MLP on the dependent chain).
//  - non-temporal stores: keep the 210MB output stream from evicting the
//    244MiB table out of the 256MiB Infinity Cache across replays.

typedef float f32x4 __attribute__((ext_vector_type(4)));
typedef int   i32x4 __attribute__((ext_vector_type(4)));

#define LPR 16  // lanes per row: 64 floats / 16B-vector

__global__ __launch_bounds__(256) void embed_gather_kernel(
    const int* __restrict__ indices,
    const f32x4* __restrict__ weight,   // row r starts at weight[r*16]
    f32x4* __restrict__ out,
    int num_rows) {
    int tid = blockIdx.x * blockDim.x + threadIdx.x;
    int g = tid >> 4;                 // group id; group handles rows 4g..4g+3
    int lane = tid & (LPR - 1);
    int r0 = g * 4;
    if (r0 >= num_rows) return;

    if (r0 + 3 < num_rows) {
        // fast path: one 16B broadcast load of 4 indices, 4 independent gathers
        i32x4 idx = *(const i32x4*)(indices + r0);
        f32x4 v0 = weight[(size_t)idx.x * LPR + lane];
        f32x4 v1 = weight[(size_t)idx.y * LPR + lane];
        f32x4 v2 = weight[(size_t)idx.z * LPR + lane];
        f32x4 v3 = weight[(size_t)idx.w * LPR + lane];
        size_t o = (size_t)r0 * LPR + lane;
        __builtin_nontemporal_store(v0, &out[o]);
        __builtin_nontemporal_store(v1, &out[o + LPR]);
        __builtin_nontemporal_store(v2, &out[o + 2 * LPR]);
        __builtin_nontemporal_store(v3, &out[o + 3 * LPR]);
    } else {
        // tail (not hit for 819200 rows, kept for generality)
        for (int r = r0; r < num_rows; ++r) {
            int src = indices[r];
            f32x4 v = weight[(size_t)src * LPR + lane];
            __builtin_nontemporal_store(v, &out[(size_t)r * LPR + lane]);
        }
    }
}

extern "C" void kernel_launch(void* const* d_in, const int* in_sizes, int n_in,
                              void* d_out, int out_size, void* d_ws, size_t ws_size,
                              hipStream_t stream) {
    const int* indices = (const int*)d_in[0];
    const f32x4* weight = (const f32x4*)d_in[1];
    f32x4* out = (f32x4*)d_out;

    int num_rows = in_sizes[0];                    // 819200
    int num_groups = (num_rows + 3) / 4;           // 4 rows per 16-lane group
    long long total_threads = (long long)num_groups * LPR;
    int block = 256;
    int grid = (int)((total_threads + block - 1) / block);

    embed_gather_kernel<<<grid, block, 0, stream>>>(indices, weight, out, num_rows);
}